// Round 2
// baseline (665.858 us; speedup 1.0000x reference)
//
#include <hip/hip_runtime.h>
#include <hip/hip_bf16.h>
#include <stdint.h>

typedef unsigned short u16;
typedef unsigned int u32;
typedef __bf16 bf16x8 __attribute__((ext_vector_type(8)));
typedef float f32x16 __attribute__((ext_vector_type(16)));
typedef u16 u16x4 __attribute__((ext_vector_type(4)));

typedef const __attribute__((address_space(1))) void* gas_ptr;
typedef __attribute__((address_space(3))) void* las_ptr;

#define M_DIM 8192
#define K_DIM 4096
#define N_DIM 4096
#define BK 64  // k-halfwords per staged tile (128 B per row)

__device__ __forceinline__ u16 f32_to_bf16_rne(float f) {
    u32 u = __float_as_uint(f);
    u += 0x7FFFu + ((u >> 16) & 1u);
    return (u16)(u >> 16);
}

// ---- 1) fused: max|W| reduction -> mb (float bits, atomicMax-as-uint) + cast xb -> bf16
__global__ void prep_kernel(const float* __restrict__ W, u32* __restrict__ mb,
                            const float* __restrict__ x, u16* __restrict__ y) {
    int idx = blockIdx.x * blockDim.x + threadIdx.x;
    int stride = gridDim.x * blockDim.x;

    const float4* W4 = (const float4*)W;
    float m = 0.0f;
    for (int i = idx; i < (K_DIM * N_DIM) / 4; i += stride) {
        float4 v = W4[i];
        m = fmaxf(m, fmaxf(fmaxf(fabsf(v.x), fabsf(v.y)), fmaxf(fabsf(v.z), fabsf(v.w))));
    }
#pragma unroll
    for (int off = 32; off > 0; off >>= 1)
        m = fmaxf(m, __shfl_down(m, off));
    if ((threadIdx.x & 63) == 0)
        atomicMax(mb, __float_as_uint(m));  // mb pre-zeroed; |W| >= 0 so uint-max == float-max

    const float4* x4 = (const float4*)x;
    u16x4* y4 = (u16x4*)y;
    for (int i = idx; i < (M_DIM * K_DIM) / 4; i += stride) {
        float4 v = x4[i];
        u16x4 o;
        o.x = f32_to_bf16_rne(v.x);
        o.y = f32_to_bf16_rne(v.y);
        o.z = f32_to_bf16_rne(v.z);
        o.w = f32_to_bf16_rne(v.w);
        y4[i] = o;
    }
}

// ---- 2) quantize W (K x N fp32) -> bf16 W^T (N x K). 64x64 tile, float4 loads, u16x4 stores.
//      w_q = clip(rint(W/s_w), ±127) is an integer -> exact in bf16 (truncation of fp32 bits).
__global__ __launch_bounds__(256) void quant_transpose_kernel(const float* __restrict__ W,
                                                              u16* __restrict__ Wt,
                                                              const u32* __restrict__ mb) {
    __shared__ u16 tileT[64][68];  // [n_local][k_local], padded
    const float s_inv = 128.0f / __uint_as_float(*mb);  // 1/s_w, s_w = 2*max/256 = max/128
    const int t = threadIdx.x;
    const int k0 = blockIdx.y * 64, n0 = blockIdx.x * 64;
    const int c4 = t & 15;  // float4 column group (n_local = c4*4 .. +4)
    const int r = t >> 4;   // 16 rows per pass
#pragma unroll
    for (int p = 0; p < 4; p++) {
        int kl = p * 16 + r;
        float4 v = *(const float4*)&W[(size_t)(k0 + kl) * N_DIM + n0 + c4 * 4];
        float q0 = fminf(fmaxf(rintf(v.x * s_inv), -127.f), 127.f);
        float q1 = fminf(fmaxf(rintf(v.y * s_inv), -127.f), 127.f);
        float q2 = fminf(fmaxf(rintf(v.z * s_inv), -127.f), 127.f);
        float q3 = fminf(fmaxf(rintf(v.w * s_inv), -127.f), 127.f);
        tileT[c4 * 4 + 0][kl] = (u16)(__float_as_uint(q0) >> 16);
        tileT[c4 * 4 + 1][kl] = (u16)(__float_as_uint(q1) >> 16);
        tileT[c4 * 4 + 2][kl] = (u16)(__float_as_uint(q2) >> 16);
        tileT[c4 * 4 + 3][kl] = (u16)(__float_as_uint(q3) >> 16);
    }
    __syncthreads();
    const int k4 = t & 15;  // u16x4 along k
    const int nr = t >> 4;
#pragma unroll
    for (int p = 0; p < 4; p++) {
        int nl = p * 16 + nr;
        u16x4 v = *(const u16x4*)&tileT[nl][k4 * 4];  // (nl*68 + k4*4)*2 is 8B-aligned
        *(u16x4*)&Wt[(size_t)(n0 + nl) * K_DIM + k0 + k4 * 4] = v;
    }
}

// ---- 3) GEMM: out[M][N] = s_w * (A[M][K] @ Bt[N][K]^T) + bias
// 128x128 tile, BK=64, 4 waves; each wave 64x64 via 2x2 of mfma_f32_32x32x16_bf16.
// LDS layout XOR-swizzled: physical 16B chunk p = logical chunk c ^ (row & 7).
//   - staging chunk g (1 KB = 8 rows x 128 B): lane l -> row g*8+(l>>3), fetches logical
//     chunk (l&7)^(l>>3); LDS dst = base + l*16 (wave-uniform base, hw lane scatter).
//   - fragment read (k-step s): logical chunk c = 2s+(lane>>5); physical p = c^(lane&7);
//     8 bank-quads x 8 lanes distinct rows = conflict-free 8-phase b128.
__global__ __launch_bounds__(256) void gemm_kernel(const u16* __restrict__ A,
                                                   const u16* __restrict__ Bt,
                                                   const float* __restrict__ bias,
                                                   const u32* __restrict__ mb,
                                                   float* __restrict__ out) {
    __shared__ u16 As[128 * BK];  // 16 KB
    __shared__ u16 Bs[128 * BK];  // 16 KB

    const int tid = threadIdx.x;
    const int wave = tid >> 6;
    const int lane = tid & 63;
    const int m0 = blockIdx.y * 128;
    const int n0 = blockIdx.x * 128;

    // staging source for chunk g = wave*4 + c
    const int srow = lane >> 3;           // row within 8-row chunk
    const int schunk = (lane & 7) ^ srow; // logical 16B k-chunk this lane fetches

    const u16* Ag[4];
    const u16* Bg[4];
    u16* Asl[4];
    u16* Bsl[4];
#pragma unroll
    for (int c = 0; c < 4; c++) {
        int g = wave * 4 + c;
        Ag[c] = A + (size_t)(m0 + g * 8 + srow) * K_DIM + schunk * 8;
        Bg[c] = Bt + (size_t)(n0 + g * 8 + srow) * K_DIM + schunk * 8;
        Asl[c] = &As[g * 512];
        Bsl[c] = &Bs[g * 512];
    }

    const int wm = wave >> 1;  // wave's 64-row block
    const int wn = wave & 1;   // wave's 64-col block
    const int l31 = lane & 31;
    const int lhi = lane >> 5;

    const float s_w = __uint_as_float(*mb) * (1.0f / 128.0f);

    f32x16 acc[2][2];
#pragma unroll
    for (int i = 0; i < 2; i++)
#pragma unroll
        for (int j = 0; j < 2; j++)
#pragma unroll
            for (int r = 0; r < 16; r++) acc[i][j][r] = 0.0f;

    // fragment row bases (halfword offsets); row&7 == lane&7 for all of them
    const int ar0 = (wm * 64 + l31) * BK;
    const int ar1 = (wm * 64 + 32 + l31) * BK;
    const int br0 = (wn * 64 + l31) * BK;
    const int br1 = (wn * 64 + 32 + l31) * BK;

    for (int k0 = 0; k0 < K_DIM; k0 += BK) {
        __syncthreads();  // prior tile's ds_reads done before overwrite
#pragma unroll
        for (int c = 0; c < 4; c++) {
            __builtin_amdgcn_global_load_lds((gas_ptr)(Ag[c] + k0), (las_ptr)Asl[c], 16, 0, 0);
            __builtin_amdgcn_global_load_lds((gas_ptr)(Bg[c] + k0), (las_ptr)Bsl[c], 16, 0, 0);
        }
        __syncthreads();  // vmcnt(0) drain: staged tile visible

#pragma unroll
        for (int s = 0; s < 4; s++) {
            const int p = ((s << 1) + lhi) ^ (lane & 7);  // physical chunk
            bf16x8 a0 = *(const bf16x8*)&As[ar0 + p * 8];
            bf16x8 a1 = *(const bf16x8*)&As[ar1 + p * 8];
            bf16x8 b0 = *(const bf16x8*)&Bs[br0 + p * 8];
            bf16x8 b1 = *(const bf16x8*)&Bs[br1 + p * 8];
            acc[0][0] = __builtin_amdgcn_mfma_f32_32x32x16_bf16(a0, b0, acc[0][0], 0, 0, 0);
            acc[0][1] = __builtin_amdgcn_mfma_f32_32x32x16_bf16(a0, b1, acc[0][1], 0, 0, 0);
            acc[1][0] = __builtin_amdgcn_mfma_f32_32x32x16_bf16(a1, b0, acc[1][0], 0, 0, 0);
            acc[1][1] = __builtin_amdgcn_mfma_f32_32x32x16_bf16(a1, b1, acc[1][1], 0, 0, 0);
        }
    }

    // C/D layout (32x32): col = lane&31, row = (reg&3) + 8*(reg>>2) + 4*(lane>>5)  [m74/m101]
#pragma unroll
    for (int j = 0; j < 2; j++) {
        const int col = n0 + wn * 64 + j * 32 + l31;
        const float bv = bias[col];
#pragma unroll
        for (int i = 0; i < 2; i++) {
            const int rbase = m0 + wm * 64 + i * 32 + 4 * lhi;
#pragma unroll
            for (int r = 0; r < 16; r++) {
                const int row = rbase + (r & 3) + 8 * (r >> 2);
                out[(size_t)row * N_DIM + col] = s_w * acc[i][j][r] + bv;
            }
        }
    }
}

extern "C" void kernel_launch(void* const* d_in, const int* in_sizes, int n_in,
                              void* d_out, int out_size, void* d_ws, size_t ws_size,
                              hipStream_t stream) {
    const float* xb = (const float*)d_in[0];  // 8192 x 4096 fp32
    const float* W = (const float*)d_in[1];   // 4096 x 4096 fp32
    const float* b = (const float*)d_in[2];   // 4096 fp32
    float* out = (float*)d_out;               // 8192 x 4096 fp32

    // ws layout: [0,4): maxabs bits | [256, 256+64M): xb bf16 | then W^T bf16 (32M)
    u32* mb = (u32*)d_ws;
    u16* xb_bf = (u16*)((char*)d_ws + 256);
    u16* wqt = (u16*)((char*)d_ws + 256 + (size_t)M_DIM * K_DIM * 2);

    hipMemsetAsync(d_ws, 0, 4, stream);  // ws is poisoned 0xAA; atomicMax needs 0 init
    prep_kernel<<<2048, 256, 0, stream>>>(W, mb, xb, xb_bf);
    quant_transpose_kernel<<<dim3(N_DIM / 64, K_DIM / 64), 256, 0, stream>>>(W, wqt, mb);
    gemm_kernel<<<dim3(N_DIM / 128, M_DIM / 128), 256, 0, stream>>>(xb_bf, wqt, b, mb, out);
}